// Round 6
// baseline (1377.283 us; speedup 1.0000x reference)
//
#include <hip/hip_runtime.h>

#define NTAGS  256
#define TLEN   512
#define BATCH  256
#define QS     68            // padded quarter stride (floats)
#define NEGINF (-3.0e38f)

typedef float v2f __attribute__((ext_vector_type(2)));

// Packed dual-fp32 add (CDNA VOP3P, full rate: 1 instr = 2 adds).
__device__ __forceinline__ v2f pk_add(v2f a, v2f b) {
    v2f d;
    asm("v_pk_add_f32 %0, %1, %2" : "=v"(d) : "v"(a), "v"(b));
    return d;
}

// One workgroup (1024 threads) per batch. Wave w owns columns 16w..16w+15;
// lane l: c = 16w + (l&15), quarter h = l>>4 scans prevs [64h, 64h+64).
// Scan: DESCENDING p with >= take —— last-taken == smallest index among
// maxima == jnp.argmax first-max. Packed halves track even/odd p classes,
// merged with explicit min-index tie-break. Adds via v_pk_add_f32 (4 ops/elem
// instead of 5). Cross-quarter combine: shfl_xor butterfly (r5-proven).
__global__ __launch_bounds__(1024, 4)
void viterbi_dp(const float* __restrict__ emis,   // [B][T][N]
                const float* __restrict__ mask,   // [B][T]
                const float* __restrict__ trans,  // [N][N]
                float* __restrict__ out)          // [B] scores ++ [B][T] paths (float)
{
    __shared__ __align__(16) float aSh[2][4 * QS];         // padded alpha, ping-pong
    __shared__ unsigned char bptL[(TLEN - 1) * NTAGS];     // 130816 B
    __shared__ float endS[NTAGS];

    const int tid   = threadIdx.x;
    const int w     = tid >> 6;
    const int lane  = tid & 63;
    const int c     = (w << 4) | (lane & 15);
    const int h     = lane >> 4;
    const int pbase = h << 6;
    const int b     = blockIdx.x;

    // 32 packed transition pairs: tr2[q] = {trans[pbase+2q][c], trans[pbase+2q+1][c]}.
    // Pinned as pairs; every step's pk_add uses force VGPR residency.
    v2f tr2[32];
#pragma unroll
    for (int q = 0; q < 32; ++q) {
        tr2[q].x = trans[(pbase + 2 * q + 0) * NTAGS + c];
        tr2[q].y = trans[(pbase + 2 * q + 1) * NTAGS + c];
        asm volatile("" : "+v"(tr2[q]));
    }

    const float* eb = emis + (size_t)b * TLEN * NTAGS;
    const float* mb = mask + (size_t)b * TLEN;

    // alphas0[c] = trans[SOS=0][c] + em[b][0][c]
    float aOld = trans[c] + eb[c];
    if (h == 0) aSh[0][QS * (c >> 6) + (c & 63)] = aOld;
    __syncthreads();

    float emCur = eb[NTAGS + c];
    float mCur  = mb[1];

    int cur = 0;
    for (int t = 1; t < TLEN; ++t) {
        float emNext = 0.0f, mNext = 1.0f;
        if (t + 1 < TLEN) {
            emNext = eb[(t + 1) * NTAGS + c];
            mNext  = mb[t + 1];
        }

        const float4* a4 = (const float4*)(&aSh[cur][h * QS]);
        v2f em2; em2.x = emCur; em2.y = emCur;

        // Descending-p scan, >= take. Parity classes in packed halves.
        // Rounding exactly as reference: (alpha[p]+trans[p][c]) + em[c].
        float m0 = NEGINF, m1 = NEGINF;   // even / odd class maxima
        int   g0 = 0,      g1 = 0;        // smallest p-offset achieving them
#pragma unroll
        for (int q = 15; q >= 0; --q) {
            const float4 al = a4[q];
            v2f ahi; ahi.x = al.z; ahi.y = al.w;
            v2f shi = pk_add(pk_add(ahi, tr2[2 * q + 1]), em2);
            if (shi.x >= m0) { m0 = shi.x; g0 = 4 * q + 2; }
            if (shi.y >= m1) { m1 = shi.y; g1 = 4 * q + 3; }
            v2f alo; alo.x = al.x; alo.y = al.y;
            v2f slo = pk_add(pk_add(alo, tr2[2 * q + 0]), em2);
            if (slo.x >= m0) { m0 = slo.x; g0 = 4 * q + 0; }
            if (slo.y >= m1) { m1 = slo.y; g1 = 4 * q + 1; }
        }
        // merge parity classes: larger value wins; tie -> smaller index.
        const bool t1 = (m1 > m0) || ((m1 == m0) && (g1 < g0));
        float gb = t1 ? m1 : m0;
        int   ga = (t1 ? g1 : g0) + pbase;

        // butterfly combine across the 4 quarters (lanes xor 16, xor 32);
        // strictly larger, or equal with smaller index (= global first-max).
#pragma unroll
        for (int m = 16; m <= 32; m <<= 1) {
            const float pvv = __shfl_xor(gb, m, 64);
            const int   paa = __shfl_xor(ga, m, 64);
            const bool take = (pvv > gb) || ((pvv == gb) && (paa < ga));
            gb = take ? pvv : gb;
            ga = take ? paa : ga;
        }

        // masked blend exactly as reference: m*max + (1-m)*alpha
        const float aNew = mCur * gb + (1.0f - mCur) * aOld;
        if (h == 0)      aSh[cur ^ 1][QS * (c >> 6) + (c & 63)] = aNew;
        else if (h == 1) bptL[(t - 1) * NTAGS + c] = (unsigned char)ga;

        aOld  = aNew;
        emCur = emNext;
        mCur  = mNext;
        cur  ^= 1;
        __syncthreads();
    }

    // end_scores = alpha + trans[:, EOS=1]
    if (h == 0) endS[c] = aOld + trans[c * NTAGS + 1];
    __syncthreads();

    if (tid == 0) {
        float best = endS[0]; int arg = 0;
        for (int i = 1; i < NTAGS; ++i) {
            float v = endS[i];
            if (v > best) { best = v; arg = i; }
        }
        out[b] = best;

        // backtrace entirely from LDS
        float* pout = out + BATCH + (size_t)b * TLEN;
        int tag = arg;
        pout[TLEN - 1] = (float)tag;
        for (int t = TLEN - 2; t >= 0; --t) {
            tag = bptL[t * NTAGS + tag];
            pout[t] = (float)tag;
        }
    }
}

extern "C" void kernel_launch(void* const* d_in, const int* in_sizes, int n_in,
                              void* d_out, int out_size, void* d_ws, size_t ws_size,
                              hipStream_t stream) {
    (void)d_ws; (void)ws_size; (void)in_sizes; (void)n_in; (void)out_size;
    const float* emis  = (const float*)d_in[0];
    const float* mask  = (const float*)d_in[1];
    const float* trans = (const float*)d_in[2];
    float* out = (float*)d_out;

    viterbi_dp<<<dim3(BATCH), dim3(1024), 0, stream>>>(emis, mask, trans, out);
}